// Round 9
// baseline (197.990 us; speedup 1.0000x reference)
//
#include <hip/hip_runtime.h>
#include <hip/hip_bf16.h>

using bf16 = __hip_bfloat16;
typedef float v2f __attribute__((ext_vector_type(2)));

#define C1 1.44269504f   // log2(e)
#define C2 2.88539008f   // 2*log2(e)

__device__ __forceinline__ float fexp2(float x) { return __builtin_amdgcn_exp2f(x); }
__device__ __forceinline__ float frcp(float x)  { return __builtin_amdgcn_rcpf(x); }

__device__ __forceinline__ unsigned int f2bfbits(float f) {  // RNE float->bf16 bits
    union { float f; unsigned int u; } c; c.f = f;
    return (c.u + 0x7fffu + ((c.u >> 16) & 1u)) >> 16;
}

// gi layout: [k][b][12] of uint2 {lo = r|z<<16, hi = n} (bf16 bits, pre-scaled C1/C1/C2)
#define KSTR 12288   // uint2 per k-slice (1024*12)
// ws: gi @0 (15,728,640 B) | pegi float4[160][12] @15,728,640 (30,720 B) => 15.76 MB
#define OFF_PEGI 15728640

// ---------------------------------------------------------------
// Kernel 1: encoder + input-gate precompute. grid (4,160) x 256.
// (unchanged from r5 — proven)
// ---------------------------------------------------------------
__global__ __launch_bounds__(256) void k_encode(
    const float* __restrict__ x, const float* __restrict__ encW, const float* __restrict__ encb,
    const float* __restrict__ Wih, const float* __restrict__ bih, const float* __restrict__ bhh,
    uint2* __restrict__ gi, float4* __restrict__ pegi)
{
    const int k = blockIdx.y, t = threadIdx.x;
    const int b = blockIdx.x * 256 + t;

    __shared__ float sW[144], sbm[12], sWih[432], sbih[36], spet[12];
    __shared__ uint2 st[256 * 13];          // 26 KB staging, stride 13
    if (t < 144) sW[t]  = encW[k * 144 + t];
    if (t < 12)  sbm[t] = encb[k * 12 + t];
    for (int i = t; i < 432; i += 256) sWih[i] = Wih[i];
    if (t < 36)  sbih[t] = bih[t] + (t < 24 ? bhh[t] : 0.f);
    if (t < 12) {
        int m = t >> 1;
        float div = __expf((float)(2 * m) * (-0.7675283643313489f)); // -ln(10000)/12
        float ang = (float)k * div;
        spet[t] = ((t & 1) ? cosf(ang) : sinf(ang)) + sinf((float)k);
    }
    __syncthreads();
    if (t < 12 && blockIdx.x == 0) {
        float sr = 0.f, sz = 0.f, sn = 0.f;
        #pragma unroll
        for (int o = 0; o < 12; o++) {
            sr = fmaf(spet[o], sWih[t * 12 + o], sr);
            sz = fmaf(spet[o], sWih[(12 + t) * 12 + o], sz);
            sn = fmaf(spet[o], sWih[(24 + t) * 12 + o], sn);
        }
        pegi[k * 12 + t] = make_float4(C1 * sr, C1 * sz, C2 * sn, 0.f);
    }

    const float4* xp = reinterpret_cast<const float4*>(x + (size_t)b * 1920 + k * 12);
    float4 a0 = xp[0], a1 = xp[1], a2 = xp[2];
    float xv[12] = {a0.x,a0.y,a0.z,a0.w, a1.x,a1.y,a1.z,a1.w, a2.x,a2.y,a2.z,a2.w};

    float xs[12];
    #pragma unroll
    for (int o = 0; o < 12; o++) {
        float s = sbm[o];
        #pragma unroll
        for (int i = 0; i < 12; i++) s = fmaf(xv[i], sW[i * 12 + o], s);
        xs[o] = fmaxf(s, 0.f);
    }

    #pragma unroll
    for (int j = 0; j < 12; j++) {
        float sr = sbih[j], sz = sbih[12 + j], sn = sbih[24 + j];
        #pragma unroll
        for (int o = 0; o < 12; o++) {
            sr = fmaf(xs[o], sWih[j * 12 + o], sr);
            sz = fmaf(xs[o], sWih[(12 + j) * 12 + o], sz);
            sn = fmaf(xs[o], sWih[(24 + j) * 12 + o], sn);
        }
        st[t * 13 + j] = make_uint2(f2bfbits(C1 * sr) | (f2bfbits(C1 * sz) << 16),
                                    f2bfbits(C2 * sn));
    }
    __syncthreads();
    uint2* gbase = gi + (size_t)k * KSTR + (size_t)blockIdx.x * 3072;
    for (int i = t; i < 3072; i += 256) {
        int bl = i / 12;
        gbase[i] = st[bl * 13 + (i - bl * 12)];
    }
}

// ---------------------------------------------------------------
// Kernel 2: two GRU passes — mixed-lane SIMD over chains.
// 256 blocks x 64. Lane c*16+j owns unit j of chain blockIdx*4+c.
// ONE instruction stream advances 4 chains: one gi load (contiguous
// 384B/wave), one dot/nonlinear block, h broadcast via 12 group-
// local ds_bpermute. No other LDS use; no readlane duplication.
// ---------------------------------------------------------------
__global__ __launch_bounds__(64) void k_recur(
    const float* __restrict__ Whh, const float* __restrict__ bhh,
    const uint2* __restrict__ gi, const float4* __restrict__ pegi,
    float* __restrict__ hout)
{
    const int lane = threadIdx.x;
    const int grp  = lane >> 4;
    const int j    = lane & 15;
    const int ju   = (j < 12) ? j : 11;
    const int b    = blockIdx.x * 4 + grp;

    int ba[12];                                // group-local bpermute byte addrs
    #pragma unroll
    for (int d = 0; d < 12; d++) ba[d] = ((lane & 48) + d) << 2;

    v2f wr2[6], wz2[6], wn2[6];
    #pragma unroll
    for (int i = 0; i < 6; i++) {
        wr2[i] = (v2f){C1 * Whh[ju * 12 + 2*i],        C1 * Whh[ju * 12 + 2*i + 1]};
        wz2[i] = (v2f){C1 * Whh[(12 + ju) * 12 + 2*i], C1 * Whh[(12 + ju) * 12 + 2*i + 1]};
        wn2[i] = (v2f){C2 * Whh[(24 + ju) * 12 + 2*i], C2 * Whh[(24 + ju) * 12 + 2*i + 1]};
    }
    const float bn = C2 * bhh[24 + ju];

    const int voff = b * 12 + ju;              // per-lane element offset in a k-slice

    v2f h2[6];
    #pragma unroll
    for (int i = 0; i < 6; i++) h2[i] = (v2f){0.f, 0.f};
    float hself = 0.f, p = 1.f;                // p = 1 - hself

    uint2 buf[8];
    #pragma unroll
    for (int i = 0; i < 8; i++) buf[i] = gi[(size_t)i * KSTR + voff];

    // ---- GRU1 (only final h needed) ----
    for (int ko = 0; ko < 160; ko += 8) {
        #pragma unroll
        for (int i = 0; i < 8; i++) {
            const int k = ko + i;
            const int kp = (k + 8 > 159) ? 159 : k + 8;
            float gr = __int_as_float((int)(buf[i].x << 16));
            float gz = __int_as_float((int)(buf[i].x & 0xffff0000u));
            float gn = __int_as_float((int)(buf[i].y << 16));
            buf[i] = gi[(size_t)kp * KSTR + voff];
            v2f an = (v2f){bn, 0.f};
            v2f ar = (v2f){gr, 0.f};
            v2f az = (v2f){gz, 0.f};
            #pragma unroll
            for (int d = 0; d < 6; d++) an += wn2[d] * h2[d];   // hn first
            #pragma unroll
            for (int d = 0; d < 6; d++) { ar += wr2[d] * h2[d]; az += wz2[d] * h2[d]; }
            float hr = ar.x + ar.y;
            float hz = az.x + az.y;
            float hn = an.x + an.y;
            float r = frcp(1.f + fexp2(-hr));
            float w = frcp(1.f + fexp2(hz));        // 1 - z
            float t = fmaf(r, hn, gn);
            float e = frcp(1.f + fexp2(t));         // n = 1 - 2e
            float hj = fmaf(w, fmaf(-2.f, e, p), hself); // h + w*((1-h) - 2e)
            hself = hj; p = 1.f - hj;
            int hv = __float_as_int(hj);
            #pragma unroll
            for (int d = 0; d < 6; d++)
                h2[d] = (v2f){__int_as_float(__builtin_amdgcn_ds_bpermute(ba[2*d],     hv)),
                              __int_as_float(__builtin_amdgcn_ds_bpermute(ba[2*d + 1], hv))};
        }
    }

    // ---- GRU2 (emit h every step); gi2 = gi1 + pegi[k] ----
    float4 pb[8];
    #pragma unroll
    for (int i = 0; i < 8; i++) {
        buf[i] = gi[(size_t)i * KSTR + voff];
        pb[i]  = pegi[i * 12 + ju];
    }
    const int hoff = b * 1920 + j;             // per-lane base in hout
    for (int ko = 0; ko < 160; ko += 8) {
        #pragma unroll
        for (int i = 0; i < 8; i++) {
            const int k = ko + i;
            const int kp = (k + 8 > 159) ? 159 : k + 8;
            float gr = __int_as_float((int)(buf[i].x << 16))         + pb[i].x;
            float gz = __int_as_float((int)(buf[i].x & 0xffff0000u)) + pb[i].y;
            float gn = __int_as_float((int)(buf[i].y << 16))         + pb[i].z;
            buf[i] = gi[(size_t)kp * KSTR + voff];
            pb[i]  = pegi[kp * 12 + ju];
            v2f an = (v2f){bn, 0.f};
            v2f ar = (v2f){gr, 0.f};
            v2f az = (v2f){gz, 0.f};
            #pragma unroll
            for (int d = 0; d < 6; d++) an += wn2[d] * h2[d];
            #pragma unroll
            for (int d = 0; d < 6; d++) { ar += wr2[d] * h2[d]; az += wz2[d] * h2[d]; }
            float hr = ar.x + ar.y;
            float hz = az.x + az.y;
            float hn = an.x + an.y;
            float r = frcp(1.f + fexp2(-hr));
            float w = frcp(1.f + fexp2(hz));
            float t = fmaf(r, hn, gn);
            float e = frcp(1.f + fexp2(t));
            float hj = fmaf(w, fmaf(-2.f, e, p), hself);
            hself = hj; p = 1.f - hj;
            if (j < 12) hout[hoff + k * 12] = hj;
            int hv = __float_as_int(hj);
            #pragma unroll
            for (int d = 0; d < 6; d++)
                h2[d] = (v2f){__int_as_float(__builtin_amdgcn_ds_bpermute(ba[2*d],     hv)),
                              __int_as_float(__builtin_amdgcn_ds_bpermute(ba[2*d + 1], hv))};
        }
    }
}

// ---------------------------------------------------------------
// Kernel 3: fold + apply merged (unchanged from r8 — proven).
// grid 160 x 256.
// ---------------------------------------------------------------
__global__ __launch_bounds__(256) void k_foldapply(
    const float* __restrict__ W1, const float* __restrict__ b1,
    const float* __restrict__ W2, const float* __restrict__ b2,
    float* __restrict__ out)
{
    const int k = blockIdx.x, t = threadIdx.x;
    __shared__ float sB[12288];   // W2[k], [h][12]
    __shared__ float sb1[1024];
    __shared__ float sWc[144], sbc[12];
    {
        const float4* w2p = reinterpret_cast<const float4*>(W2 + (size_t)k * 12288);
        float4* sB4 = reinterpret_cast<float4*>(sB);
        for (int i = t; i < 3072; i += 256) sB4[i] = w2p[i];
        const float4* b1p = reinterpret_cast<const float4*>(b1 + (size_t)k * 1024);
        float4* sb14 = reinterpret_cast<float4*>(sb1);
        sb14[t] = b1p[t];
    }
    __syncthreads();
    if (t < 156) {
        const int o = (t < 144) ? (t % 12) : (t - 144);
        float s0 = 0.f, s1 = 0.f, s2 = 0.f, s3 = 0.f;
        if (t < 144) {
            const float4* va4 = reinterpret_cast<const float4*>(W1 + (size_t)k * 12288 + (size_t)(t / 12) * 1024);
            #pragma unroll 4
            for (int q = 0; q < 256; q++) {
                float4 a = va4[q];
                const float* bq = sB + q * 48 + o;
                s0 = fmaf(a.x, bq[0],  s0);
                s1 = fmaf(a.y, bq[12], s1);
                s2 = fmaf(a.z, bq[24], s2);
                s3 = fmaf(a.w, bq[36], s3);
            }
        } else {
            #pragma unroll 4
            for (int hh = 0; hh < 1024; hh += 4) {
                const float* bq = sB + hh * 12 + o;
                s0 = fmaf(sb1[hh],     bq[0],  s0);
                s1 = fmaf(sb1[hh + 1], bq[12], s1);
                s2 = fmaf(sb1[hh + 2], bq[24], s2);
                s3 = fmaf(sb1[hh + 3], bq[36], s3);
            }
        }
        float s = (s0 + s1) + (s2 + s3);
        if (t < 144) sWc[t] = s;
        else         sbc[t - 144] = s + b2[k * 12 + o];
    }
    __syncthreads();

    for (int bb = t; bb < 1024; bb += 256) {
        float* hp = out + (size_t)bb * 1920 + k * 12;
        float4* h4 = reinterpret_cast<float4*>(hp);
        float4 a0 = h4[0], a1 = h4[1], a2 = h4[2];
        float hv[12] = {a0.x,a0.y,a0.z,a0.w, a1.x,a1.y,a1.z,a1.w, a2.x,a2.y,a2.z,a2.w};
        float ov[12];
        #pragma unroll
        for (int o = 0; o < 12; o++) {
            float s = sbc[o];
            #pragma unroll
            for (int d = 0; d < 12; d++) s = fmaf(hv[d], sWc[d * 12 + o], s);
            ov[o] = s;
        }
        h4[0] = make_float4(ov[0], ov[1], ov[2],  ov[3]);
        h4[1] = make_float4(ov[4], ov[5], ov[6],  ov[7]);
        h4[2] = make_float4(ov[8], ov[9], ov[10], ov[11]);
    }
}

// ---------------------------------------------------------------
extern "C" void kernel_launch(void* const* d_in, const int* in_sizes, int n_in,
                              void* d_out, int out_size, void* d_ws, size_t ws_size,
                              hipStream_t stream)
{
    const float* x    = (const float*)d_in[0];
    const float* encW = (const float*)d_in[1];
    const float* encb = (const float*)d_in[2];
    const float* Wih  = (const float*)d_in[3];
    const float* Whh  = (const float*)d_in[4];
    const float* bih  = (const float*)d_in[5];
    const float* bhh  = (const float*)d_in[6];
    const float* W1   = (const float*)d_in[7];
    const float* b1   = (const float*)d_in[8];
    const float* W2   = (const float*)d_in[9];
    const float* b2   = (const float*)d_in[10];
    float* out = (float*)d_out;

    char* ws = (char*)d_ws;
    uint2*  gi   = (uint2*)(ws);
    float4* pegi = (float4*)(ws + OFF_PEGI);

    k_encode   <<<dim3(4, 160), 256, 0, stream>>>(x, encW, encb, Wih, bih, bhh, gi, pegi);
    k_recur    <<<dim3(256),    64,  0, stream>>>(Whh, bhh, gi, pegi, out);
    k_foldapply<<<dim3(160),    256, 0, stream>>>(W1, b1, W2, b2, out);
}